// Round 6
// baseline (679.654 us; speedup 1.0000x reference)
//
#include <hip/hip_runtime.h>
#include <math.h>

typedef unsigned short u16;
typedef unsigned int u32;
typedef __attribute__((ext_vector_type(8))) short short8;
typedef __attribute__((ext_vector_type(4))) float f32x4;

__device__ __forceinline__ float b2f(u16 u) {
    return __uint_as_float(((u32)u) << 16);
}
__device__ __forceinline__ u16 f2b(float f) {
    u32 x = __float_as_uint(f);
    return (u16)((x + 0x7fffu + ((x >> 16) & 1u)) >> 16);   // RNE
}
__device__ __forceinline__ float ldext(const void* p, size_t i, int isbf) {
    return isbf ? b2f(((const u16*)p)[i]) : ((const float*)p)[i];
}
__device__ __forceinline__ void stext(void* p, size_t i, int isbf, float v) {
    if (isbf) ((u16*)p)[i] = f2b(v);
    else ((float*)p)[i] = v;
}
// async global->LDS, 16B per lane; lds base wave-uniform (HW adds lane*16)
__device__ __forceinline__ void gl2lds16(const u16* g, u16* l) {
    __builtin_amdgcn_global_load_lds(
        (const __attribute__((address_space(1))) u32*)(const void*)g,
        (__attribute__((address_space(3))) u32*)(void*)l, 16, 0, 0);
}
__device__ __forceinline__ void unpack8(uint4 w, float* f) {
    const u32* pw = (const u32*)&w;
#pragma unroll
    for (int k = 0; k < 4; ++k) {
        f[2 * k]     = __uint_as_float(pw[k] << 16);
        f[2 * k + 1] = __uint_as_float(pw[k] & 0xffff0000u);
    }
}

// ---------- dtype detector: 1 if h is bf16, 0 if f32 ----------
__global__ void detect_k(const void* __restrict__ h, int* __restrict__ flag) {
    __shared__ int cnt;
    if (threadIdx.x == 0) cnt = 0;
    __syncthreads();
    const u16* p = (const u16*)h;
    int local = 0;
    for (int i = threadIdx.x; i < 4096; i += 256) {
        int e = (p[i] >> 7) & 0xFF;
        if (e != 0 && (e < 110 || e > 133)) local++;
    }
    atomicAdd(&cnt, local);
    __syncthreads();
    if (threadIdx.x == 0) *flag = (cnt < 256) ? 1 : 0;
}

// ---------- all 4 weight transposes in one launch ----------
__global__ void transpose_all(const void* __restrict__ qkv_w, const void* __restrict__ proj_w,
                              const void* __restrict__ w1, const void* __restrict__ w2,
                              u16* __restrict__ WqkvT, u16* __restrict__ WprojT,
                              u16* __restrict__ W1T, u16* __restrict__ W2T,
                              const int* __restrict__ flag) {
    int isbf = *flag;
    int idx = blockIdx.x * 256 + threadIdx.x;
    if (idx < 196608) {                       // qkv_w [256][768]
        int r = idx / 768, c = idx - r * 768;
        WqkvT[c * 256 + r] = f2b(ldext(qkv_w, idx, isbf));
    } else if (idx < 262144) {                // proj_w [256][256]
        int i = idx - 196608; int r = i >> 8, c = i & 255;
        WprojT[c * 256 + r] = f2b(ldext(proj_w, i, isbf));
    } else if (idx < 393216) {                // w1 [256][512]
        int i = idx - 262144; int r = i >> 9, c = i & 511;
        W1T[c * 256 + r] = f2b(ldext(w1, i, isbf));
    } else {                                  // w2 [512][256]
        int i = idx - 393216; int r = i >> 8, c = i & 255;
        W2T[c * 512 + r] = f2b(ldext(w2, i, isbf));
    }
}

// ---------- arsinh norm: y = w[c]*asinh(x)+b[c]; ext/forced-bf16 in -> bf16 out ----------
__global__ void norm_k(const void* __restrict__ xb, size_t xoff,
                       const void* __restrict__ w, const void* __restrict__ b,
                       u16* __restrict__ y, const int* __restrict__ flag, int force_bf) {
    int isbf = *flag;
    int xisbf = force_bf ? 1 : isbf;
    size_t base = ((size_t)blockIdx.x * 256 + threadIdx.x) * 4;
    int c0 = (int)(base & 255);
    float v[4];
    if (xisbf) {
        uint2 raw = *reinterpret_cast<const uint2*>((const u16*)xb + xoff + base);
        const u16* px = reinterpret_cast<const u16*>(&raw);
#pragma unroll
        for (int j = 0; j < 4; ++j) v[j] = b2f(px[j]);
    } else {
        float4 r = *reinterpret_cast<const float4*>((const float*)xb + xoff + base);
        v[0] = r.x; v[1] = r.y; v[2] = r.z; v[3] = r.w;
    }
    u16 o[4];
#pragma unroll
    for (int j = 0; j < 4; ++j)
        o[j] = f2b(ldext(w, c0 + j, isbf) * asinhf(v[j]) + ldext(b, c0 + j, isbf));
    *reinterpret_cast<uint2*>(y + base) = *reinterpret_cast<uint2*>(o);
}

// ======== GEMM v2: A-resident full-K LDS, N-tile loop, swizzled banks ========
// C[M][N] = A[M][K] @ BT[N][K]^T + bias.  TM in {128,64}, K in {256,512}.
// EPI 0: store bf16 out1         1: GELU -> bf16 out1
// EPI 4: + bf16 res -> ext out1  5: + ext res -> bf16 out1(hnew) AND norm2 -> bf16 out2
template <int EPI, int TM, int K>
__global__ __launch_bounds__(256) void gemm2(
    const u16* __restrict__ A, const u16* __restrict__ BT, const void* __restrict__ bias,
    const void* __restrict__ resb, void* __restrict__ out1, u16* __restrict__ out2,
    const void* __restrict__ nw, const void* __restrict__ nb,
    int N, const int* __restrict__ flag) {
    __shared__ __align__(16) u16 lA[TM * K];        // 64 KB for both configs
    __shared__ __align__(16) u16 lB[2][128 * 32];   // 8 KB x2 double buffer
    const int isbf = *flag;
    const int tid = threadIdx.x;
    const int lane = tid & 63;
    const int wave = tid >> 6;
    const int waveM = wave >> 1, waveN = wave & 1;
    const int m0 = blockIdx.x * TM;
    const int NT = N >> 7;
    constexpr int MT = TM / 32;        // mi tiles per wave: 4 (TM=128) / 2 (TM=64)
    constexpr int CHPR = K / 8;        // 16B chunks per A row
    constexpr int SPW = (TM * K * 2 / 1024) / 4;    // A slots per wave = 16

    // ---- stage whole A tile (swizzled: chunk p holds global chunk p^(row&7)) ----
#pragma unroll
    for (int q = 0; q < SPW; ++q) {
        int s = wave * SPW + q;
        int chunk = s * 64 + lane;
        int row = chunk / CHPR;
        int p = chunk % CHPR;
        int c = p ^ (row & 7);
        gl2lds16(&A[(size_t)(m0 + row) * K + c * 8], &lA[s * 512]);
    }

    const int lrow = lane & 15;
    const int ko = (lane >> 4) * 8;
    const int rquad = (lane >> 4) * 4;
    constexpr int KI = K / 32;

    for (int nt = 0; nt < NT; ++nt) {
        const int n0 = nt << 7;
        f32x4 acc[MT][4];
#pragma unroll
        for (int mi = 0; mi < MT; ++mi)
#pragma unroll
            for (int ni = 0; ni < 4; ++ni)
#pragma unroll
                for (int r = 0; r < 4; ++r) acc[mi][ni][r] = 0.f;

        __syncthreads();   // prev tile's reads done before overwriting lB[0]
        // stage B k-chunk 0 (swizzled: chunk p holds global chunk p^((row>>1)&3))
#pragma unroll
        for (int q = 0; q < 2; ++q) {
            int s = wave * 2 + q;
            int chunk = s * 64 + lane;
            int row = chunk >> 2, p = chunk & 3;
            int c = p ^ ((row >> 1) & 3);
            gl2lds16(&BT[(size_t)(n0 + row) * K + c * 8], &lB[0][s * 512]);
        }
#pragma unroll
        for (int i = 0; i < KI; ++i) {
            __syncthreads();    // staged data (A and lB[i&1]) visible; prev reads drained
            if (i + 1 < KI) {
                int k1 = (i + 1) * 32;
#pragma unroll
                for (int q = 0; q < 2; ++q) {
                    int s = wave * 2 + q;
                    int chunk = s * 64 + lane;
                    int row = chunk >> 2, p = chunk & 3;
                    int c = p ^ ((row >> 1) & 3);
                    gl2lds16(&BT[(size_t)(n0 + row) * K + k1 + c * 8], &lB[(i + 1) & 1][s * 512]);
                }
            }
            const int k0 = i * 32;
            short8 af[MT], bfr[4];
#pragma unroll
            for (int mi = 0; mi < MT; ++mi) {
                int r = waveM * (TM / 2) + mi * 16 + lrow;
                int p = ((k0 + ko) >> 3) ^ (r & 7);
                af[mi] = *reinterpret_cast<const short8*>(&lA[r * K + p * 8]);
            }
#pragma unroll
            for (int ni = 0; ni < 4; ++ni) {
                int r = waveN * 64 + ni * 16 + lrow;
                int p = (ko >> 3) ^ ((r >> 1) & 3);
                bfr[ni] = *reinterpret_cast<const short8*>(&lB[i & 1][r * 32 + p * 8]);
            }
#pragma unroll
            for (int mi = 0; mi < MT; ++mi)
#pragma unroll
                for (int ni = 0; ni < 4; ++ni)
                    acc[mi][ni] = __builtin_amdgcn_mfma_f32_16x16x32_bf16(af[mi], bfr[ni], acc[mi][ni], 0, 0, 0);
        }
        // ---- epilogue for this N-tile ----
        const int ccol = lane & 15;
#pragma unroll
        for (int mi = 0; mi < MT; ++mi)
#pragma unroll
            for (int ni = 0; ni < 4; ++ni) {
                int colg = n0 + waveN * 64 + ni * 16 + ccol;
                float bb = ldext(bias, colg, isbf);
                float nwc = 0.f, nbc = 0.f;
                if (EPI == 5) { nwc = ldext(nw, colg, isbf); nbc = ldext(nb, colg, isbf); }
#pragma unroll
                for (int r = 0; r < 4; ++r) {
                    int rowg = m0 + waveM * (TM / 2) + mi * 16 + rquad + r;
                    size_t idx = (size_t)rowg * N + colg;
                    float v = acc[mi][ni][r] + bb;
                    if (EPI == 0) {
                        ((u16*)out1)[idx] = f2b(v);
                    } else if (EPI == 1) {
                        v = 0.5f * v * (1.f + erff(v * 0.70710678118654752f));
                        ((u16*)out1)[idx] = f2b(v);
                    } else if (EPI == 4) {
                        v += b2f(((const u16*)resb)[idx]);
                        stext(out1, idx, isbf, v);
                    } else {  // EPI 5: proj + residual, write hnew AND norm2(hnew)
                        v += ldext(resb, idx, isbf);
                        ((u16*)out1)[idx] = f2b(v);
                        out2[idx] = f2b(nwc * asinhf(v) + nbc);
                    }
                }
            }
    }
}

// ---------- legacy GEMM (chunked fallback path only) ----------
template <int EPI>
__global__ __launch_bounds__(256) void gemm_bt(
    const u16* __restrict__ A, const u16* __restrict__ BT, const void* __restrict__ bias,
    const void* __restrict__ resb, size_t resoff, void* __restrict__ outb, size_t outoff,
    int N, int K, const int* __restrict__ flag) {
    __shared__ __align__(16) u16 lA[128 * 32];
    __shared__ __align__(16) u16 lB[128 * 32];
    const int isbf = *flag;
    const int tid = threadIdx.x;
    const int lane = tid & 63;
    const int wave = tid >> 6;
    const int waveM = wave >> 1, waveN = wave & 1;
    const int m0 = blockIdx.y * 128;
    const int n0 = blockIdx.x * 128;
    f32x4 acc[4][4];
#pragma unroll
    for (int mi = 0; mi < 4; ++mi)
#pragma unroll
        for (int ni = 0; ni < 4; ++ni)
#pragma unroll
            for (int r = 0; r < 4; ++r) acc[mi][ni][r] = 0.f;
    const int lrow = lane & 15;
    const int ko = (lane >> 4) * 8;
    for (int k0 = 0; k0 < K; k0 += 32) {
        __syncthreads();
#pragma unroll
        for (int q = 0; q < 2; ++q) {
            int s = wave * 2 + q;
            int e0 = (s * 64 + lane) * 8;
            int row = e0 >> 5, col = e0 & 31;
            gl2lds16(&A[(size_t)(m0 + row) * K + k0 + col], &lA[s * 512]);
            gl2lds16(&BT[(size_t)(n0 + row) * K + k0 + col], &lB[s * 512]);
        }
        __syncthreads();
        short8 af[4], bfr[4];
#pragma unroll
        for (int mi = 0; mi < 4; ++mi)
            af[mi] = *reinterpret_cast<const short8*>(&lA[(waveM * 64 + mi * 16 + lrow) * 32 + ko]);
#pragma unroll
        for (int ni = 0; ni < 4; ++ni)
            bfr[ni] = *reinterpret_cast<const short8*>(&lB[(waveN * 64 + ni * 16 + lrow) * 32 + ko]);
#pragma unroll
        for (int mi = 0; mi < 4; ++mi)
#pragma unroll
            for (int ni = 0; ni < 4; ++ni)
                acc[mi][ni] = __builtin_amdgcn_mfma_f32_16x16x32_bf16(af[mi], bfr[ni], acc[mi][ni], 0, 0, 0);
    }
    const int rquad = (lane >> 4) * 4;
    const int ccol = lane & 15;
#pragma unroll
    for (int mi = 0; mi < 4; ++mi)
#pragma unroll
        for (int ni = 0; ni < 4; ++ni) {
            int colg = n0 + waveN * 64 + ni * 16 + ccol;
            float bb = ldext(bias, colg, isbf);
#pragma unroll
            for (int r = 0; r < 4; ++r) {
                int rowg = m0 + waveM * 64 + mi * 16 + rquad + r;
                size_t idx = (size_t)rowg * N + colg;
                float v = acc[mi][ni][r] + bb;
                if (EPI == 0) {
                    ((u16*)outb)[outoff + idx] = f2b(v);
                } else if (EPI == 1) {
                    v = 0.5f * v * (1.f + erff(v * 0.70710678118654752f));
                    ((u16*)outb)[outoff + idx] = f2b(v);
                } else {
                    v += ldext(resb, resoff + idx, isbf);
                    stext(outb, outoff + idx, isbf, v);
                }
            }
        }
}

// ---------- neighborhood attention: thread = (pixel, head), all in registers ----------
__global__ __launch_bounds__(256) void attn_k(const u16* __restrict__ qkv, u16* __restrict__ out) {
    const int t = blockIdx.x * 256 + threadIdx.x;
    const int head = t & 7;
    const int p = t >> 3;
    const int b = p >> 12;
    const int ij = p & 4095;
    const int i = ij >> 6, j = ij & 63;
    int r0 = i - 1; r0 = r0 < 0 ? 0 : (r0 > 61 ? 61 : r0);
    int c0 = j - 1; c0 = c0 < 0 ? 0 : (c0 > 61 ? 61 : c0);

    const u16* qp = qkv + (size_t)p * 768 + head * 32;
    float q[32];
#pragma unroll
    for (int ch = 0; ch < 4; ++ch)
        unpack8(*reinterpret_cast<const uint4*>(qp + ch * 8), q + ch * 8);

    const float qscale = 0.17677669529663687f;
    int nbp[9];
    float sc[9];
#pragma unroll
    for (int dr = 0; dr < 3; ++dr)
#pragma unroll
        for (int dc = 0; dc < 3; ++dc) {
            int nb = dr * 3 + dc;
            int np_ = b * 4096 + (r0 + dr) * 64 + (c0 + dc);
            nbp[nb] = np_;
            const u16* kp = qkv + (size_t)np_ * 768 + 256 + head * 32;
            float dot = 0.f;
#pragma unroll
            for (int ch = 0; ch < 4; ++ch) {
                float kf[8];
                unpack8(*reinterpret_cast<const uint4*>(kp + ch * 8), kf);
#pragma unroll
                for (int e = 0; e < 8; ++e) dot += q[ch * 8 + e] * kf[e];
            }
            sc[nb] = dot * qscale;
        }
    float mx = sc[0];
#pragma unroll
    for (int nb = 1; nb < 9; ++nb) mx = fmaxf(mx, sc[nb]);
    float s = 0.f;
#pragma unroll
    for (int nb = 0; nb < 9; ++nb) { sc[nb] = __expf(sc[nb] - mx); s += sc[nb]; }
    float inv = 1.f / s;

    float acc[32];
#pragma unroll
    for (int e = 0; e < 32; ++e) acc[e] = 0.f;
#pragma unroll
    for (int nb = 0; nb < 9; ++nb) {
        const u16* vp = qkv + (size_t)nbp[nb] * 768 + 512 + head * 32;
        float wgt = sc[nb] * inv;
#pragma unroll
        for (int ch = 0; ch < 4; ++ch) {
            float vf[8];
            unpack8(*reinterpret_cast<const uint4*>(vp + ch * 8), vf);
#pragma unroll
            for (int e = 0; e < 8; ++e) acc[ch * 8 + e] += wgt * vf[e];
        }
    }
    u16 ob[32];
#pragma unroll
    for (int e = 0; e < 32; ++e) ob[e] = f2b(acc[e]);
    uint4* ov = reinterpret_cast<uint4*>(ob);
    uint4* og = reinterpret_cast<uint4*>(out + (size_t)p * 256 + head * 32);
#pragma unroll
    for (int ch = 0; ch < 4; ++ch) og[ch] = ov[ch];
}

extern "C" void kernel_launch(void* const* d_in, const int* in_sizes, int n_in,
                              void* d_out, int out_size, void* d_ws, size_t ws_size,
                              hipStream_t stream) {
    const void* h      = d_in[0];
    const void* qkv_w  = d_in[1];
    const void* qkv_b  = d_in[2];
    const void* proj_w = d_in[3];
    const void* proj_b = d_in[4];
    const void* n1_w   = d_in[5];
    const void* n1_b   = d_in[6];
    const void* n2_w   = d_in[7];
    const void* n2_b   = d_in[8];
    const void* w1     = d_in[9];
    const void* b1     = d_in[10];
    const void* w2     = d_in[11];
    const void* b2     = d_in[12];

    char* ws = (char*)d_ws;
    u16* WqkvT  = (u16*)(ws + 0);          // [768][256]
    u16* WprojT = (u16*)(ws + 393216);     // [256][256]
    u16* W1T    = (u16*)(ws + 524288);     // [512][256]
    u16* W2T    = (u16*)(ws + 786432);     // [256][512]
    int* Flag   = (int*)(ws + 1048576);
    char* bufs  = ws + 1049600;

    size_t avail = ws_size > 1049600 ? ws_size - 1049600 : 0;
    int CHUNK = 4096;
    if (avail >= (size_t)65536 * 2048) CHUNK = 65536;
    else if (avail >= (size_t)16384 * 2048) CHUNK = 16384;
    else if (avail >= (size_t)8192 * 2048) CHUNK = 8192;

    u16* H1 = (u16*)bufs;                          // [65536][256] bf16
    u16* S  = (u16*)(bufs + (size_t)CHUNK * 512);  // [CHUNK][768] bf16

    detect_k<<<1, 256, 0, stream>>>(h, Flag);
    transpose_all<<<2048, 256, 0, stream>>>(qkv_w, proj_w, w1, w2,
                                            WqkvT, WprojT, W1T, W2T, Flag);

    if (CHUNK == 65536) {
        u16* HNS = S;                         // hnew bf16 (qkv dead after attn)
        u16* T   = S + (size_t)65536 * 256;   // mlp hidden [65536][512]
        norm_k<<<16384, 256, 0, stream>>>(h, 0, n1_w, n1_b, H1, Flag, 0);
        gemm2<0, 128, 256><<<512, 256, 0, stream>>>(H1, WqkvT, qkv_b, nullptr, S, nullptr,
                                                    nullptr, nullptr, 768, Flag);
        attn_k<<<2048, 256, 0, stream>>>(S, H1);
        gemm2<5, 128, 256><<<512, 256, 0, stream>>>(H1, WprojT, proj_b, h, HNS, H1,
                                                    n2_w, n2_b, 256, Flag);
        gemm2<1, 128, 256><<<512, 256, 0, stream>>>(H1, W1T, b1, nullptr, T, nullptr,
                                                    nullptr, nullptr, 512, Flag);
        gemm2<4, 64, 512><<<1024, 256, 0, stream>>>(T, W2T, b2, HNS, d_out, nullptr,
                                                    nullptr, nullptr, 256, Flag);
    } else {
        const int NCH = 65536 / CHUNK;
        for (int c = 0; c < NCH; ++c) {
            size_t off = (size_t)c * CHUNK * 256;
            norm_k<<<CHUNK / 4, 256, 0, stream>>>(h, off, n1_w, n1_b, H1, Flag, 0);
            { dim3 g(6, CHUNK / 128);
              gemm_bt<0><<<g, 256, 0, stream>>>(H1, WqkvT, qkv_b, nullptr, 0, S, 0, 768, 256, Flag); }
            attn_k<<<CHUNK / 32, 256, 0, stream>>>(S, H1);
            { dim3 g(2, CHUNK / 128);
              gemm_bt<2><<<g, 256, 0, stream>>>(H1, WprojT, proj_b, h, off, d_out, off, 256, 256, Flag); }
        }
        for (int c = 0; c < NCH; ++c) {
            size_t off = (size_t)c * CHUNK * 256;
            norm_k<<<CHUNK / 4, 256, 0, stream>>>(d_out, off, n2_w, n2_b, H1, Flag, 0);
            { dim3 g(4, CHUNK / 128);
              gemm_bt<1><<<g, 256, 0, stream>>>(H1, W1T, b1, nullptr, 0, S, 0, 512, 256, Flag); }
            { dim3 g(2, CHUNK / 128);
              gemm_bt<2><<<g, 256, 0, stream>>>(S, W2T, b2, d_out, off, d_out, off, 256, 512, Flag); }
        }
    }
}